// Round 2
// baseline (343.269 us; speedup 1.0000x reference)
//
#include <hip/hip_runtime.h>
#include <cmath>
#include <algorithm>

#define NUM_LEVELS 16
#define TABLE_SIZE 524288
#define TMASK (TABLE_SIZE - 1)
#define HASH_PRIME 2654435761u
#define T_SAMPLES 192
#define BLOCK 256
#define PTS 64          // points per block; 4 waves split the 16 levels
#define CHUNK 4096      // entries per conversion chunk

typedef _Float16 f16;
typedef f16 f16x4 __attribute__((ext_vector_type(4)));
typedef f16 f16x8 __attribute__((ext_vector_type(8)));
typedef float f32x4 __attribute__((ext_vector_type(4)));

struct LvlParams {
    float s[NUM_LEVELS];
    int   res[NUM_LEVELS];
    int   hashed[NUM_LEVELS];
    int   off[NUM_LEVELS];    // entry offset into compact f16 table (4096-aligned)
    int   used[NUM_LEVELS];   // entries actually referenced at this level
};

__device__ __forceinline__ float softplus10(float x) {
    float t = 10.0f * x;
    float e = __expf(-fabsf(t));
    return (fmaxf(t, 0.0f) + __logf(1.0f + e)) * 0.1f;
}

// Packed-f16 bilinear lerp: corners arrive as packed f16 pairs straight from
// the gather (no unpack/dequant).
__device__ __forceinline__ f16x4 lerp4h(f16x4 c00, f16x4 c01, f16x4 c10, f16x4 c11,
                                        float fx, float fy) {
    float gx = 1.0f - fx, gy = 1.0f - fy;
    f16 w00 = (f16)(gx * gy), w01 = (f16)(gx * fy);
    f16 w10 = (f16)(fx * gy), w11 = (f16)(fx * fy);
    f16x4 v00 = {w00, w00, w00, w00}, v01 = {w01, w01, w01, w01};
    f16x4 v10 = {w10, w10, w10, w10}, v11 = {w11, w11, w11, w11};
    return c00 * v00 + c01 * v01 + c10 * v10 + c11 * v11;
}

// fp32 fallback lerp (QT=false path), result rounded to f16 for the MFMA.
__device__ __forceinline__ f16x4 lerp4f(f32x4 c00, f32x4 c01, f32x4 c10, f32x4 c11,
                                        float fx, float fy) {
    float w00 = (1.0f - fx) * (1.0f - fy), w01 = (1.0f - fx) * fy;
    float w10 = fx * (1.0f - fy),          w11 = fx * fy;
    f32x4 a = c00 * w00 + c01 * w01 + c10 * w10 + c11 * w11;
    return __builtin_convertvector(a, f16x4);
}

// ---- prep: pack W0 into MFMA-B-fragment f16 order ----
__global__ void prep(const float* __restrict__ W0, f16* __restrict__ w0f) {
    const int t = threadIdx.x;
    #pragma unroll
    for (int i = 0; i < 16; ++i) {
        int f = t * 16 + i;
        int j = f & 7, lx = (f >> 3) & 15, q = (f >> 7) & 3, nt = (f >> 9) & 3, kc = f >> 11;
        int k = kc * 32 + q * 8 + j;
        int n = nt * 16 + lx;
        w0f[f] = (f16)W0[k * 64 + n];
    }
}

// ---- prep_tables: pure streaming f32 -> f16 convert of used entries ----
__global__ void prep_tables(const float* __restrict__ emb, f16* __restrict__ embq,
                            const LvlParams lp) {
    const int l    = blockIdx.y;
    const int used = lp.used[l];
    const int base = blockIdx.x * CHUNK;          // entry base within level
    if (base >= used) return;
    const int t = threadIdx.x;
    const float* src = emb + ((size_t)l * TABLE_SIZE + base) * 4;
    f16* dst = embq + (size_t)(lp.off[l] + base) * 4;
    #pragma unroll
    for (int i = 0; i < 16; ++i) {
        int e = t + 256 * i;
        if (base + e < used) {
            f32x4 v = *(const f32x4*)(src + (size_t)e * 4);
            *(f16x4*)(dst + (size_t)e * 4) = __builtin_convertvector(v, f16x4);
        }
    }
}

// QT=true: gathers from compact f16 tables; all 16 corner gathers of a wave's
// 4 levels are issued before any lerp so load latency overlaps lerp VALU.
template<bool QT>
__launch_bounds__(BLOCK, 8)
__global__ void nerf_fused(const float* __restrict__ x,
                           const float* __restrict__ emb,
                           const f16* __restrict__ embq,
                           const f16* __restrict__ w0f,
                           const float* __restrict__ b0,
                           const float* __restrict__ W1,
                           const float* __restrict__ b1,
                           float* __restrict__ out,
                           const LvlParams lp) {
    // Transposed feats tile: feT[level][point][dim], 16*64*4 f16 = 8 KB.
    __shared__ __align__(16) f16 feT[NUM_LEVELS * PTS * 4];

    const int tid  = threadIdx.x;
    const int lane = tid & 63;
    const int w    = __builtin_amdgcn_readfirstlane(tid >> 6);   // wave-uniform -> SGPR

    // ---- ray setup: 192 = 3*64, so each block lies inside ONE ray ----
    const int ray = blockIdx.x / 3;                    // block-uniform (scalar)
    const int t   = (blockIdx.x - ray * 3) * PTS + lane;

    const float2 o  = *(const float2*)(x + (size_t)ray * (T_SAMPLES * 2));
    const float2 ep = *(const float2*)(x + (size_t)ray * (T_SAMPLES * 2) + (T_SAMPLES - 1) * 2);
    float rdx = ep.x - o.x, rdy = ep.y - o.y;
    float inv = 1.0f / sqrtf(rdx * rdx + rdy * rdy);
    rdx *= inv; rdy *= inv;
    const float z = (float)((double)t * (2.0 / 191.0));
    float px = fminf(fmaxf(o.x + rdx * z, -1.0f), 1.0f);
    float py = fminf(fmaxf(o.y + rdy * z, -1.0f), 1.0f);
    const float ux = (px + 1.0f) * 0.5f;
    const float uy = (py + 1.0f) * 0.5f;

    // this wave's levels: w, w+4, w+8, w+12 (only l3 can be hashed)
    const int l3h = lp.hashed[w + 12];                 // scalar

    if (QT) {
        // ---- stage 1: compute all indices, issue ALL 16 gathers ----
        f16x4 ca[4][4];            // [level][corner: 00,01,10,11] = 32 VGPRs
        float fxs[4], fys[4];
        #pragma unroll
        for (int li = 0; li < 4; ++li) {
            const int l = w + li * 4;                  // scalar
            const float s = lp.s[l];                   // s_load
            float posx = ux * s + 0.5f, posy = uy * s + 0.5f;
            float pfx = floorf(posx), pfy = floorf(posy);
            fxs[li] = posx - pfx; fys[li] = posy - pfy;
            int cx = (int)pfx, cy = (int)pfy;
            int i00, i01, i10, i11;
            if (li == 3 && l3h) {
                unsigned hy0 = (unsigned)cy * HASH_PRIME;
                unsigned hy1 = hy0 + HASH_PRIME;       // (cy+1)*PRIME, mul -> add
                i00 = (int)(((unsigned)cx ^ hy0) & TMASK);
                i01 = (int)(((unsigned)cx ^ hy1) & TMASK);
                i10 = (int)(((unsigned)(cx + 1) ^ hy0) & TMASK);
                i11 = (int)(((unsigned)(cx + 1) ^ hy1) & TMASK);
            } else {
                // NOTE: reference has NO bounds clamp; used[] covers the overrun tail.
                const int res = lp.res[l];
                i00 = cy * res + cx; i10 = i00 + 1;
                i01 = i00 + res;     i11 = i01 + 1;
            }
            const f16x4* tb = (const f16x4*)embq + lp.off[l];
            ca[li][0] = tb[i00]; ca[li][1] = tb[i01];
            ca[li][2] = tb[i10]; ca[li][3] = tb[i11];
        }
        // ---- stage 2: consume in issue order (vmcnt drains naturally) ----
        #pragma unroll
        for (int li = 0; li < 4; ++li) {
            const int l = w + li * 4;
            *(f16x4*)&feT[(l * PTS + lane) * 4] =
                lerp4h(ca[li][0], ca[li][1], ca[li][2], ca[li][3], fxs[li], fys[li]);
        }
    } else {
        // fallback: per-level immediate consume (f32 corners would blow VGPRs)
        #pragma unroll
        for (int li = 0; li < 4; ++li) {
            const int l = w + li * 4;
            const float s = lp.s[l];
            float posx = ux * s + 0.5f, posy = uy * s + 0.5f;
            float pfx = floorf(posx), pfy = floorf(posy);
            float fx = posx - pfx, fy = posy - pfy;
            int cx = (int)pfx, cy = (int)pfy;
            int i00, i01, i10, i11;
            if (li == 3 && l3h) {
                unsigned hy0 = (unsigned)cy * HASH_PRIME;
                unsigned hy1 = hy0 + HASH_PRIME;
                i00 = (int)(((unsigned)cx ^ hy0) & TMASK);
                i01 = (int)(((unsigned)cx ^ hy1) & TMASK);
                i10 = (int)(((unsigned)(cx + 1) ^ hy0) & TMASK);
                i11 = (int)(((unsigned)(cx + 1) ^ hy1) & TMASK);
            } else {
                const int res = lp.res[l];
                i00 = cy * res + cx; i10 = i00 + 1;
                i01 = i00 + res;     i11 = i01 + 1;
            }
            const f32x4* tb = (const f32x4*)(emb + (size_t)l * (TABLE_SIZE * 4));
            f32x4 a = tb[i00], b = tb[i01], c = tb[i10], d = tb[i11];
            *(f16x4*)&feT[(l * PTS + lane) * 4] = lerp4f(a, b, c, d, fx, fy);
        }
    }

    __syncthreads();   // all 4 waves' feature quarters visible

    // ---- MLP: wave w computes h for its own 16 points (M=16, N=64) ----
    const int lx = lane & 15, q = lane >> 4;
    const int p  = w * 16 + lx;

    f32x4 acc[4];
    #pragma unroll
    for (int nt = 0; nt < 4; ++nt) acc[nt] = (f32x4)(0.0f);

    #pragma unroll
    for (int kc = 0; kc < 2; ++kc) {
        // A-fragment: k = kc*32 + q*8 + j ; feats k = level*4 + dim
        const int la = kc * 8 + 2 * q;
        f16x4 lo = *(const f16x4*)&feT[(la * PTS + p) * 4];
        f16x4 hi = *(const f16x4*)&feT[((la + 1) * PTS + p) * 4];
        f16x8 afr = __builtin_shufflevector(lo, hi, 0, 1, 2, 3, 4, 5, 6, 7);
        #pragma unroll
        for (int nt = 0; nt < 4; ++nt) {
            f16x8 bfr = *(const f16x8*)(w0f + (size_t)(((kc * 4 + nt) * 4 + q) * 16 + lx) * 8);
            acc[nt] = __builtin_amdgcn_mfma_f32_16x16x32_f16(afr, bfr, acc[nt], 0, 0, 0);
        }
    }

    // ---- epilogue: softplus10 -> dot W1 -> reduce over 16 col-lanes ----
    // Constants folded: t = 10*acc + (10*b0);  contribution = (max+log1p) * (0.1*W1)
    float b010[4], w1s[4];
    #pragma unroll
    for (int nt = 0; nt < 4; ++nt) {
        b010[nt] = b0[nt * 16 + lx] * 10.0f;
        w1s[nt]  = W1[nt * 16 + lx] * 0.1f;
    }
    const float b1v = b1[0];
    const float d0 = (float)(1.0 / 192.0);
    const float d1 = (float)(2.0 / 191.0);

    float part[4];
    #pragma unroll
    for (int r = 0; r < 4; ++r) {
        float pp = 0.0f;
        #pragma unroll
        for (int nt = 0; nt < 4; ++nt) {
            float t10 = fmaf(acc[nt][r], 10.0f, b010[nt]);
            float e   = __expf(-fabsf(t10));
            float sp  = fmaxf(t10, 0.0f) + __logf(1.0f + e);
            pp = fmaf(sp, w1s[nt], pp);
        }
        pp += __shfl_xor(pp, 1, 64);
        pp += __shfl_xor(pp, 2, 64);
        pp += __shfl_xor(pp, 4, 64);
        pp += __shfl_xor(pp, 8, 64);
        part[r] = pp;
    }
    if (lx == 0) {
        const int g0 = blockIdx.x * PTS + w * 16 + q * 4;   // multiple of 4
        const int tt = g0 % T_SAMPLES;
        f32x4 ov;
        ov.x = softplus10(part[0] + b1v) * (tt == 0 ? d0 : d1);
        ov.y = softplus10(part[1] + b1v) * d1;
        ov.z = softplus10(part[2] + b1v) * d1;
        ov.w = softplus10(part[3] + b1v) * d1;
        *(f32x4*)(out + g0) = ov;
    }
}

extern "C" void kernel_launch(void* const* d_in, const int* in_sizes, int n_in,
                              void* d_out, int out_size, void* d_ws, size_t ws_size,
                              hipStream_t stream) {
    const float* x   = (const float*)d_in[0];
    const float* emb = (const float*)d_in[1];
    const float* W0  = (const float*)d_in[2];
    const float* b0  = (const float*)d_in[3];
    const float* W1  = (const float*)d_in[4];
    const float* b1  = (const float*)d_in[5];
    float* out = (float*)d_out;

    // ws layout: [0,8192) w0f; embq (f16) at 16384.
    char* ws = (char*)d_ws;
    f16* w0f  = (f16*)ws;
    f16* embq = (f16*)(ws + 16384);

    // Replicate numpy's level constants with the same host libm double ops.
    LvlParams lp;
    const double bb = std::exp((std::log(2048.0) - std::log(2.0)) / 15.0);
    int off = 0, maxUsed = 0;
    for (int l = 0; l < NUM_LEVELS; ++l) {
        double sc = 2.0 * std::pow(bb, (double)l) - 1.0;
        int rr = (int)std::ceil(sc) + 1;
        lp.s[l] = (float)sc;
        lp.res[l] = rr;
        lp.hashed[l] = ((long long)rr * (long long)rr > (long long)TABLE_SIZE) ? 1 : 0;
        int used;
        if (lp.hashed[l]) {
            used = TABLE_SIZE;
        } else {
            // Reference does NOT clamp corners: max idx = cmax*res + cmax where
            // cmax = floor(s+0.5)+1 (reachable at u=1). Cover it, + margin for
            // float(s) vs double(s) coordinate rounding.
            long long cmax = (long long)std::floor(sc + 0.5) + 1;
            long long u = cmax * (long long)rr + cmax + 1 + (rr + 2);
            used = (int)std::min((long long)TABLE_SIZE, u);
        }
        lp.off[l]  = off;
        lp.used[l] = used;
        off += (used + CHUNK - 1) & ~(CHUNK - 1);   // keep chunks level-aligned
        if (used > maxUsed) maxUsed = used;
    }
    const size_t need = 16384 + (size_t)off * 4 * sizeof(f16);   // ~16.5 MB
    const bool useQ = ws_size >= need;

    prep<<<1, 256, 0, stream>>>(W0, w0f);

    const int nblk = out_size / PTS;   // 1572864/64 = 24576
    if (useQ) {
        dim3 pg((maxUsed + CHUNK - 1) / CHUNK, NUM_LEVELS);
        prep_tables<<<pg, 256, 0, stream>>>(emb, embq, lp);
        nerf_fused<true><<<nblk, BLOCK, 0, stream>>>(x, emb, embq, w0f,
                                                     b0, W1, b1, out, lp);
    } else {
        nerf_fused<false><<<nblk, BLOCK, 0, stream>>>(x, emb, embq, w0f,
                                                      b0, W1, b1, out, lp);
    }
}